// Round 4
// baseline (182.240 us; speedup 1.0000x reference)
//
#include <hip/hip_runtime.h>

// Problem dims
#define B_   16
#define C_   256
#define HW_  3136      // 56*56
#define W_   56
#define CR_  128
#define KKG_ 144
#define G_   16
#define NPOS (B_*HW_)  // 50176
#define EPS_ 1e-5f
#define NBLK 784       // 16 b * 49 p-tiles of 64

typedef float f32x4 __attribute__((ext_vector_type(4)));
typedef short s16x8 __attribute__((ext_vector_type(8)));
typedef short s16x4 __attribute__((ext_vector_type(4)));

// ws layout (bytes):
//   t2   : [128 o][16 b][3136 p] bf16 = 12,845,056
//   kern : [16 b][144 o2][3136 p] bf16 = 14,450,688
//   gp   : [784 blk][256] f32 (sum[128]|sumsq[128]) = 802,816
//   stats: scale[128]|shift[128] f32 = 1024
//   wbfr : [128][256] bf16 = 65,536
//   wbfs : [144][128] bf16 = 36,864
#define T2_OFF_B    0
#define KERN_OFF_B  12845056
#define GP_OFF_B    27295744
#define STAT_OFF_B  28098560
#define WBFR_OFF_B  28099584
#define WBFS_OFF_B  28165120

__device__ inline unsigned short f2bf(float f) {
    unsigned u = __float_as_uint(f);
    u += 0x7fff + ((u >> 16) & 1);          // RNE
    return (unsigned short)(u >> 16);
}
__device__ inline float bf2f(unsigned short h) {
    return __uint_as_float(((unsigned)h) << 16);
}

// ---------------------------------------------------------------------------
// K0: cast w_reduce (32768) and w_span (18432) to bf16 once.
// ---------------------------------------------------------------------------
__global__ __launch_bounds__(256) void prep_cast(
    const float* __restrict__ w_reduce, const float* __restrict__ w_span,
    unsigned short* __restrict__ wbfr, unsigned short* __restrict__ wbfs)
{
    int idx = blockIdx.x * 256 + threadIdx.x;
    if (idx < 32768) {
        wbfr[idx] = f2bf(w_reduce[idx]);
    } else {
        int k = idx - 32768;
        if (k < 18432) wbfs[k] = f2bf(w_span[k]);
    }
}

// ---------------------------------------------------------------------------
// K1: t2[o][b][p] = sum_c w_reduce[o][c] * x[b][c][p]   (bf16 MFMA 16x16x32)
// Block 128o x 64p, 4 waves 2x2 over (64o x 32p). Double-buffered B tile
// (one barrier per chunk, next chunk's loads issued before the barrier).
// A-fragments loaded directly from global (w is L2-resident, K-contiguous).
// BN partials per block -> gp (no atomics).
// ---------------------------------------------------------------------------
__global__ __launch_bounds__(256) void reduce_mfma(
    const float* __restrict__ x, const unsigned short* __restrict__ wbfr,
    unsigned short* __restrict__ t2, float* __restrict__ gp)
{
    __shared__ __align__(16) short bs_[2][64 * 40];  // [p][c-chunk 32] pad->40
    __shared__ float redp[128][2], redq[128][2];

    const int tid = threadIdx.x;
    const int lane = tid & 63, wv = tid >> 6;
    const int q = lane >> 4, i = lane & 15;
    const int mrow = (wv >> 1) * 64, nrow = (wv & 1) * 32;
    const int blk = blockIdx.x;
    const int b = blk / 49;
    const int p0 = (blk % 49) * 64;

    const float* xb = x + (size_t)b * C_ * HW_ + p0;
    const int cp = tid >> 4, rq = tid & 15;          // B staging role

    f32x4 acc[4][2] = {};

    // prologue: stage chunk 0 into buffer 0
    {
        const float* s0 = xb + (size_t)(2 * cp) * HW_ + rq * 4;
        float4 va = *(const float4*)s0;
        float4 vb = *(const float4*)(s0 + HW_);
        float a4[4] = {va.x, va.y, va.z, va.w};
        float b4[4] = {vb.x, vb.y, vb.z, vb.w};
        #pragma unroll
        for (int j = 0; j < 4; j++) {
            unsigned pk = (unsigned)f2bf(a4[j]) | ((unsigned)f2bf(b4[j]) << 16);
            *(unsigned*)&bs_[0][(rq * 4 + j) * 40 + 2 * cp] = pk;
        }
    }

    #pragma unroll
    for (int k = 0; k < 8; k++) {
        const int buf = k & 1;
        // issue next chunk's global loads early (latency hidden by MFMA)
        float4 va_n, vb_n;
        if (k < 7) {
            const float* s0 = xb + (size_t)((k + 1) * 32 + 2 * cp) * HW_ + rq * 4;
            va_n = *(const float4*)s0;
            vb_n = *(const float4*)(s0 + HW_);
        }
        // A fragments direct from global (L2-hit)
        s16x8 af[4];
        #pragma unroll
        for (int mt = 0; mt < 4; mt++)
            af[mt] = *(const s16x8*)&wbfr[(size_t)(mrow + mt * 16 + i) * C_ + k * 32 + q * 8];
        __syncthreads();   // bs_[buf] ready
        s16x8 bfr[2];
        #pragma unroll
        for (int nt = 0; nt < 2; nt++)
            bfr[nt] = *(const s16x8*)&bs_[buf][(nrow + nt * 16 + i) * 40 + q * 8];
        #pragma unroll
        for (int mt = 0; mt < 4; mt++)
            #pragma unroll
            for (int nt = 0; nt < 2; nt++)
                acc[mt][nt] = __builtin_amdgcn_mfma_f32_16x16x32_bf16(
                    af[mt], bfr[nt], acc[mt][nt], 0, 0, 0);
        // pack next chunk into the other buffer (protected by next iter's barrier)
        if (k < 7) {
            float a4[4] = {va_n.x, va_n.y, va_n.z, va_n.w};
            float b4[4] = {vb_n.x, vb_n.y, vb_n.z, vb_n.w};
            #pragma unroll
            for (int j = 0; j < 4; j++) {
                unsigned pk = (unsigned)f2bf(a4[j]) | ((unsigned)f2bf(b4[j]) << 16);
                *(unsigned*)&bs_[buf ^ 1][(rq * 4 + j) * 40 + 2 * cp] = pk;
            }
        }
    }

    // Epilogue: D col=i -> p, row=q*4+reg -> o. Store t2[o][b][p] bf16.
    #pragma unroll
    for (int mt = 0; mt < 4; mt++) {
        #pragma unroll
        for (int nt = 0; nt < 2; nt++) {
            #pragma unroll
            for (int reg = 0; reg < 4; reg++) {
                int o = mrow + mt * 16 + q * 4 + reg;
                int p = p0 + nrow + nt * 16 + i;
                t2[((size_t)o * B_ + b) * HW_ + p] = f2bf(acc[mt][nt][reg]);
            }
        }
        #pragma unroll
        for (int reg = 0; reg < 4; reg++) {
            float v0 = acc[mt][0][reg], v1 = acc[mt][1][reg];
            float s = v0 + v1;
            float ss = v0 * v0 + v1 * v1;
            #pragma unroll
            for (int m = 1; m < 16; m <<= 1) {
                s  += __shfl_xor(s, m);
                ss += __shfl_xor(ss, m);
            }
            if (i == 0) {
                int o = mrow + mt * 16 + q * 4 + reg;
                redp[o][wv & 1] = s;
                redq[o][wv & 1] = ss;
            }
        }
    }
    __syncthreads();
    if (tid < 128)
        gp[(size_t)blk * 256 + tid] = redp[tid][0] + redp[tid][1];
    else
        gp[(size_t)blk * 256 + tid] = redq[tid - 128][0] + redq[tid - 128][1];
}

// ---------------------------------------------------------------------------
// K2: sum partials -> scale/shift. One block per channel.
// ---------------------------------------------------------------------------
__global__ __launch_bounds__(256) void bn_finalize(
    const float* __restrict__ gp, const float* __restrict__ gamma,
    const float* __restrict__ beta, float* __restrict__ stats)
{
    const int o = blockIdx.x;
    const int tid = threadIdx.x;
    float s = 0.f, ss = 0.f;
    for (int blk = tid; blk < NBLK; blk += 256) {
        s  += gp[(size_t)blk * 256 + o];
        ss += gp[(size_t)blk * 256 + 128 + o];
    }
    #pragma unroll
    for (int m = 1; m < 64; m <<= 1) {
        s  += __shfl_xor(s, m);
        ss += __shfl_xor(ss, m);
    }
    __shared__ float rs[4], rss[4];
    if ((tid & 63) == 0) { rs[tid >> 6] = s; rss[tid >> 6] = ss; }
    __syncthreads();
    if (tid == 0) {
        s  = rs[0] + rs[1] + rs[2] + rs[3];
        ss = rss[0] + rss[1] + rss[2] + rss[3];
        float inv_n = 1.0f / (float)NPOS;
        float mu = s * inv_n;
        float var = ss * inv_n - mu * mu;
        float sc = gamma[o] * rsqrtf(var + EPS_);
        stats[o] = sc;
        stats[128 + o] = beta[o] - mu * sc;
    }
}

// ---------------------------------------------------------------------------
// K3: kern[b][o2][p] = sum_o w_span[o2][o]*relu(bn(t2[o][b][p])) + b_span[o2]
// Block 144o2 x 64p. Double-buffered B tile (BN+ReLU fused in pack);
// A-fragments direct from global.
// ---------------------------------------------------------------------------
__global__ __launch_bounds__(256) void span_mfma(
    const unsigned short* __restrict__ t2, const unsigned short* __restrict__ wbfs,
    const float* __restrict__ b_span, const float* __restrict__ stats,
    unsigned short* __restrict__ kern)
{
    __shared__ __align__(16) short bs_[2][64 * 40];
    __shared__ float scs[128], shs[128], bsp[144];

    const int tid = threadIdx.x;
    const int lane = tid & 63, wv = tid >> 6;
    const int q = lane >> 4, i = lane & 15;
    const int blk = blockIdx.x;
    const int b = blk / 49;
    const int p0 = (blk % 49) * 64;

    if (tid < 128) { scs[tid] = stats[tid]; shs[tid] = stats[128 + tid]; }
    if (tid < 144) bsp[tid] = b_span[tid];
    __syncthreads();

    const int op = tid >> 4, seg = tid & 15;   // B staging role

    f32x4 acc[9] = {};

    // prologue: stage chunk 0 into buffer 0 (BN+ReLU fused)
    {
        int cA = 2 * op;
        const unsigned short* tA = t2 + ((size_t)cA * B_ + b) * HW_ + p0 + seg * 4;
        s16x4 vA = *(const s16x4*)tA;
        s16x4 vB = *(const s16x4*)(tA + (size_t)B_ * HW_);
        float sA = scs[cA], hA = shs[cA];
        float sB = scs[cA + 1], hB = shs[cA + 1];
        #pragma unroll
        for (int j = 0; j < 4; j++) {
            float fa = fmaxf(fmaf(bf2f((unsigned short)vA[j]), sA, hA), 0.0f);
            float fb = fmaxf(fmaf(bf2f((unsigned short)vB[j]), sB, hB), 0.0f);
            unsigned pk = (unsigned)f2bf(fa) | ((unsigned)f2bf(fb) << 16);
            *(unsigned*)&bs_[0][(seg * 4 + j) * 40 + 2 * op] = pk;
        }
    }

    #pragma unroll
    for (int k = 0; k < 4; k++) {
        const int buf = k & 1;
        s16x4 vA_n, vB_n;
        int cA_n = 0;
        if (k < 3) {
            cA_n = (k + 1) * 32 + 2 * op;
            const unsigned short* tA = t2 + ((size_t)cA_n * B_ + b) * HW_ + p0 + seg * 4;
            vA_n = *(const s16x4*)tA;
            vB_n = *(const s16x4*)(tA + (size_t)B_ * HW_);
        }
        s16x8 af[9];
        #pragma unroll
        for (int mt = 0; mt < 9; mt++)
            af[mt] = *(const s16x8*)&wbfs[(size_t)(mt * 16 + i) * CR_ + k * 32 + q * 8];
        __syncthreads();
        s16x8 bfrag = *(const s16x8*)&bs_[buf][(wv * 16 + i) * 40 + q * 8];
        #pragma unroll
        for (int mt = 0; mt < 9; mt++)
            acc[mt] = __builtin_amdgcn_mfma_f32_16x16x32_bf16(af[mt], bfrag, acc[mt], 0, 0, 0);
        if (k < 3) {
            float sA = scs[cA_n], hA = shs[cA_n];
            float sB = scs[cA_n + 1], hB = shs[cA_n + 1];
            #pragma unroll
            for (int j = 0; j < 4; j++) {
                float fa = fmaxf(fmaf(bf2f((unsigned short)vA_n[j]), sA, hA), 0.0f);
                float fb = fmaxf(fmaf(bf2f((unsigned short)vB_n[j]), sB, hB), 0.0f);
                unsigned pk = (unsigned)f2bf(fa) | ((unsigned)f2bf(fb) << 16);
                *(unsigned*)&bs_[buf ^ 1][(seg * 4 + j) * 40 + 2 * op] = pk;
            }
        }
    }

    // Epilogue: kern[b][o2][p] bf16; col=i -> p, row=q*4+reg -> o2
    const int p = p0 + wv * 16 + i;
    #pragma unroll
    for (int mt = 0; mt < 9; mt++) {
        #pragma unroll
        for (int reg = 0; reg < 4; reg++) {
            int o2 = mt * 16 + q * 4 + reg;
            kern[((size_t)b * KKG_ + o2) * HW_ + p] = f2bf(acc[mt][reg] + bsp[o2]);
        }
    }
}

// ---------------------------------------------------------------------------
// K4: out[b, g*16+d, p] = sum_kk x[b, g*16+d, p+off(kk)] * kern[b, kk*16+g, p]
// 4-pixel threads (W=56: 4-groups never cross rows). float4 row loads +
// 2 edge scalars; s16x4 kern loads; float4 stores.
// ---------------------------------------------------------------------------
__global__ __launch_bounds__(256) void involution_apply(
    const float* __restrict__ x, const unsigned short* __restrict__ kern,
    float* __restrict__ out)
{
    int gtid = blockIdx.x * 256 + threadIdx.x;
    int pix4 = gtid % 784;             // h*14 + w-group
    int bg   = gtid / 784;
    int g = bg & 15;
    int b = bg >> 4;
    int h  = pix4 / 14;
    int w0 = (pix4 % 14) * 4;
    int pix = h * W_ + w0;

    // kernel values for 4 pixels x 9 taps
    const unsigned short* kb = kern + (size_t)b * KKG_ * HW_ + pix;
    float kv[9][4];
    #pragma unroll
    for (int kk = 0; kk < 9; kk++) {
        s16x4 kvv = *(const s16x4*)&kb[(size_t)(kk * G_ + g) * HW_];
        #pragma unroll
        for (int j = 0; j < 4; j++) kv[kk][j] = bf2f((unsigned short)kvv[j]);
    }

    const bool wl = (w0 > 0), wr = (w0 < W_ - 4);
    const float* xb = x + (size_t)(b * C_ + g * 16) * HW_;
    float* ob = out + (size_t)(b * C_ + g * 16) * HW_ + pix;

    #pragma unroll 4
    for (int d = 0; d < 16; d++) {
        const float* xd = xb + (size_t)d * HW_;
        float a0 = 0.f, a1 = 0.f, a2 = 0.f, a3 = 0.f;
        #pragma unroll
        for (int di = 0; di < 3; di++) {
            int hh = h + di - 1;
            if (hh < 0 || hh >= W_) continue;
            const float* rowp = xd + hh * W_ + w0;
            float4 m = *(const float4*)rowp;          // 16B-aligned
            float e0 = wl ? rowp[-1] : 0.f;
            float e5 = wr ? rowp[4]  : 0.f;
            float e[6] = {e0, m.x, m.y, m.z, m.w, e5};
            #pragma unroll
            for (int dj = 0; dj < 3; dj++) {
                const float* kvt = kv[di * 3 + dj];
                a0 = fmaf(e[0 + dj], kvt[0], a0);
                a1 = fmaf(e[1 + dj], kvt[1], a1);
                a2 = fmaf(e[2 + dj], kvt[2], a2);
                a3 = fmaf(e[3 + dj], kvt[3], a3);
            }
        }
        *(float4*)(ob + (size_t)d * HW_) = make_float4(a0, a1, a2, a3);
    }
}

extern "C" void kernel_launch(void* const* d_in, const int* in_sizes, int n_in,
                              void* d_out, int out_size, void* d_ws, size_t ws_size,
                              hipStream_t stream) {
    const float* x        = (const float*)d_in[0];
    const float* w_reduce = (const float*)d_in[1];
    // d_in[2] = b_reduce: unused — per-channel bias cancels exactly in BN.
    const float* gamma    = (const float*)d_in[3];
    const float* beta     = (const float*)d_in[4];
    const float* w_span   = (const float*)d_in[5];
    const float* b_span   = (const float*)d_in[6];
    float* out = (float*)d_out;

    char* wsb = (char*)d_ws;
    unsigned short* t2   = (unsigned short*)(wsb + T2_OFF_B);
    unsigned short* kern = (unsigned short*)(wsb + KERN_OFF_B);
    float*          gp    = (float*)(wsb + GP_OFF_B);
    float*          stats = (float*)(wsb + STAT_OFF_B);
    unsigned short* wbfr = (unsigned short*)(wsb + WBFR_OFF_B);
    unsigned short* wbfs = (unsigned short*)(wsb + WBFS_OFF_B);

    prep_cast<<<200, 256, 0, stream>>>(w_reduce, w_span, wbfr, wbfs);
    reduce_mfma<<<NBLK, 256, 0, stream>>>(x, wbfr, t2, gp);
    bn_finalize<<<128, 256, 0, stream>>>(gp, gamma, beta, stats);
    span_mfma<<<NBLK, 256, 0, stream>>>(t2, wbfs, b_span, stats, kern);
    involution_apply<<<NBLK, 256, 0, stream>>>(x, kern, out);
}

// Round 6
// 167.843 us; speedup vs baseline: 1.0858x; 1.0858x over previous
//
#include <hip/hip_runtime.h>

// Problem dims
#define B_   16
#define C_   256
#define HW_  3136      // 56*56
#define W_   56
#define CR_  128
#define KKG_ 144
#define G_   16
#define NPOS (B_*HW_)  // 50176
#define EPS_ 1e-5f
#define NBLK 784       // 16 b * 49 p-tiles of 64

typedef float f32x4 __attribute__((ext_vector_type(4)));
typedef short s16x8 __attribute__((ext_vector_type(8)));
typedef short s16x4 __attribute__((ext_vector_type(4)));

// ws layout (bytes):
//   t_g     : [784 blk][64 p][128 o] bf16 = 12,845,056  (B-fragment-ready rows)
//   gp      : [784][256] f32 (sum|sumsq) = 802,816
//   stats   : scale[128]|shift[128] f32 = 1024
//   wbfr_sw : 32768 bf16 fragment-order = 65,536
//   wbfs_sw : 18432 bf16 fragment-order = 36,864
#define TG_OFF_B    0
#define GP_OFF_B    12845056
#define STAT_OFF_B  13647872
#define WBFR_OFF_B  13648896
#define WBFS_OFF_B  13714432

__device__ inline unsigned short f2bf(float f) {
    unsigned u = __float_as_uint(f);
    u += 0x7fff + ((u >> 16) & 1);          // RNE
    return (unsigned short)(u >> 16);
}
__device__ inline float bf2f(unsigned short h) {
    return __uint_as_float(((unsigned)h) << 16);
}

// ---------------------------------------------------------------------------
// K0: cast weights to bf16 AND pre-swizzle into MFMA A-fragment wave order:
// a wave's A-frag load for (chunk k, mt) is one coalesced 16B/lane read.
//   A-frag layout: lane=q*16+i holds A[m=i][k=q*8+e], m=o row, k=c.
// 200 blocks x 256 = 51200 threads = 32768 + 18432 exactly.
// ---------------------------------------------------------------------------
__global__ __launch_bounds__(256) void prep_cast(
    const float* __restrict__ w_reduce, const float* __restrict__ w_span,
    unsigned short* __restrict__ wbfr_sw, unsigned short* __restrict__ wbfs_sw)
{
    int idx = blockIdx.x * 256 + threadIdx.x;
    if (idx < 32768) {
        int row = idx >> 8, col = idx & 255;
        int k = col >> 5, qq = (col >> 3) & 3, e = col & 7;
        int half = row >> 6, mt = (row >> 4) & 3, ii = row & 15;
        int lane = qq * 16 + ii;
        wbfr_sw[((((k * 2 + half) * 4 + mt) * 64) + lane) * 8 + e] = f2bf(w_reduce[idx]);
    } else {
        int s2 = idx - 32768;   // < 18432
        int row = s2 >> 7, col = s2 & 127;
        int k = col >> 5, qq = (col >> 3) & 3, e = col & 7;
        int mt = row >> 4, ii = row & 15;
        int lane = qq * 16 + ii;
        wbfs_sw[(((k * 9 + mt) * 64) + lane) * 8 + e] = f2bf(w_span[s2]);
    }
}

// ---------------------------------------------------------------------------
// K1: t_g[blk][p][o] = (w_reduce @ x)-tile, bf16; BN partials -> gp.
// 128o x 64p per block; A-frags coalesced from swizzled global (L2-hit),
// B transposed via LDS (R3-proven). D bounced through LDS -> coalesced store.
// ---------------------------------------------------------------------------
__global__ __launch_bounds__(256, 2) void reduce_mfma(
    const float* __restrict__ x, const unsigned short* __restrict__ wbfr_sw,
    unsigned short* __restrict__ t_g, float* __restrict__ gp)
{
    __shared__ __align__(16) short bs_[64 * 40];     // [p][32 c] pad->40
    __shared__ __align__(16) short t_tile[64 * 130]; // [p][128 o] pad->130
    __shared__ float redp[256], redq[256];

    const int tid = threadIdx.x;
    const int lane = tid & 63, wv = tid >> 6;
    const int q = lane >> 4, i = lane & 15;
    const int half = wv >> 1, mrow = half * 64, nrow = (wv & 1) * 32;
    const int blk = blockIdx.x;
    const int b = blk / 49;
    const int p0 = (blk % 49) * 64;

    const float* xb = x + (size_t)b * C_ * HW_ + p0;
    const int cp = tid >> 4, rq = tid & 15;          // B staging role

    f32x4 acc[4][2] = {};

    for (int k = 0; k < 8; k++) {
        // A-frags: one coalesced 16B/lane read each (wave-uniform base)
        s16x8 af[4];
        #pragma unroll
        for (int mt = 0; mt < 4; mt++)
            af[mt] = *(const s16x8*)&wbfr_sw[((((k * 2 + half) * 4 + mt) * 64) + lane) * 8];
        // B staging: transpose x[c][p] -> bs_[p][c], c-pairs packed b32
        const float* s0 = xb + (size_t)(k * 32 + 2 * cp) * HW_ + rq * 4;
        float4 va = *(const float4*)s0;
        float4 vb = *(const float4*)(s0 + HW_);
        float a4[4] = {va.x, va.y, va.z, va.w};
        float b4[4] = {vb.x, vb.y, vb.z, vb.w};
        #pragma unroll
        for (int j = 0; j < 4; j++) {
            unsigned pk = (unsigned)f2bf(a4[j]) | ((unsigned)f2bf(b4[j]) << 16);
            *(unsigned*)&bs_[(rq * 4 + j) * 40 + 2 * cp] = pk;
        }
        __syncthreads();
        s16x8 bfr[2];
        #pragma unroll
        for (int nt = 0; nt < 2; nt++)
            bfr[nt] = *(const s16x8*)&bs_[(nrow + nt * 16 + i) * 40 + q * 8];
        #pragma unroll
        for (int mt = 0; mt < 4; mt++)
            #pragma unroll
            for (int nt = 0; nt < 2; nt++)
                acc[mt][nt] = __builtin_amdgcn_mfma_f32_16x16x32_bf16(
                    af[mt], bfr[nt], acc[mt][nt], 0, 0, 0);
        __syncthreads();
    }

    // Epilogue: t_tile[p][o] bf16 + BN partials
    #pragma unroll
    for (int mt = 0; mt < 4; mt++) {
        #pragma unroll
        for (int nt = 0; nt < 2; nt++) {
            s16x4 hv;
            #pragma unroll
            for (int reg = 0; reg < 4; reg++) hv[reg] = (short)f2bf(acc[mt][nt][reg]);
            *(s16x4*)&t_tile[(nrow + nt * 16 + i) * 130 + mrow + mt * 16 + q * 4] = hv;
        }
        #pragma unroll
        for (int reg = 0; reg < 4; reg++) {
            float v0 = acc[mt][0][reg], v1 = acc[mt][1][reg];
            float s = v0 + v1, ss = v0 * v0 + v1 * v1;
            #pragma unroll
            for (int m = 1; m < 16; m <<= 1) {
                s  += __shfl_xor(s, m);
                ss += __shfl_xor(ss, m);
            }
            if (i == 0) {
                int o = mrow + mt * 16 + q * 4 + reg;
                redp[o * 2 + (wv & 1)] = s;
                redq[o * 2 + (wv & 1)] = ss;
            }
        }
    }
    __syncthreads();
    if (tid < 128)
        gp[(size_t)blk * 256 + tid] = redp[tid * 2] + redp[tid * 2 + 1];
    else
        gp[(size_t)blk * 256 + tid] = redq[(tid - 128) * 2] + redq[(tid - 128) * 2 + 1];

    // Bounce LDS -> global, fully coalesced: t_g[blk][p][o]
    {
        const int p = tid >> 2, part = tid & 3;
        const short* src = &t_tile[p * 130 + part * 32];
        unsigned short* dst = t_g + ((size_t)blk * 64 + p) * 128 + part * 32;
        *(s16x8*)(dst)      = *(const s16x8*)(src);
        *(s16x8*)(dst + 8)  = *(const s16x8*)(src + 8);
        *(s16x8*)(dst + 16) = *(const s16x8*)(src + 16);
        *(s16x8*)(dst + 24) = *(const s16x8*)(src + 24);
    }
}

// ---------------------------------------------------------------------------
// K2: sum partials -> scale/shift. One block per channel.
// ---------------------------------------------------------------------------
__global__ __launch_bounds__(256) void bn_finalize(
    const float* __restrict__ gp, const float* __restrict__ gamma,
    const float* __restrict__ beta, float* __restrict__ stats)
{
    const int o = blockIdx.x;
    const int tid = threadIdx.x;
    float s = 0.f, ss = 0.f;
    for (int blk = tid; blk < NBLK; blk += 256) {
        s  += gp[(size_t)blk * 256 + o];
        ss += gp[(size_t)blk * 256 + 128 + o];
    }
    #pragma unroll
    for (int m = 1; m < 64; m <<= 1) {
        s  += __shfl_xor(s, m);
        ss += __shfl_xor(ss, m);
    }
    __shared__ float rs[4], rss[4];
    if ((tid & 63) == 0) { rs[tid >> 6] = s; rss[tid >> 6] = ss; }
    __syncthreads();
    if (tid == 0) {
        s  = rs[0] + rs[1] + rs[2] + rs[3];
        ss = rss[0] + rss[1] + rss[2] + rss[3];
        float inv_n = 1.0f / (float)NPOS;
        float mu = s * inv_n;
        float var = ss * inv_n - mu * mu;
        float sc = gamma[o] * rsqrtf(var + EPS_);
        stats[o] = sc;
        stats[128 + o] = beta[o] - mu * sc;
    }
}

// ---------------------------------------------------------------------------
// K3: span GEMM (zero-barrier K-loop, B-frags direct from t_g, BN+ReLU in
// register) -> kern tile in LDS -> involution. kern never touches HBM.
// ---------------------------------------------------------------------------
__global__ __launch_bounds__(256, 2) void span_invol(
    const float* __restrict__ x, const unsigned short* __restrict__ t_g,
    const unsigned short* __restrict__ wbfs_sw, const float* __restrict__ b_span,
    const float* __restrict__ stats, float* __restrict__ out)
{
    __shared__ __align__(16) short kt[64 * 152];   // [p][144 o2] pad->152
    __shared__ float scs[128], shs[128], bsp[144];

    const int tid = threadIdx.x;
    const int lane = tid & 63, wv = tid >> 6;
    const int q = lane >> 4, i = lane & 15;
    const int blk = blockIdx.x;
    const int b = blk / 49;
    const int p0 = (blk % 49) * 64;

    if (tid < 128) { scs[tid] = stats[tid]; shs[tid] = stats[128 + tid]; }
    if (tid < 144) bsp[tid] = b_span[tid];
    __syncthreads();

    // ---- span GEMM: each wave owns 16 p rows, all 144 o2 ----
    {
        const int pl = wv * 16 + i;
        const unsigned short* trow = t_g + ((size_t)blk * 64 + pl) * 128;
        f32x4 acc[9] = {};
        for (int k = 0; k < 4; k++) {
            s16x8 raw = *(const s16x8*)&trow[k * 32 + q * 8];
            float4 sc0 = *(const float4*)&scs[k * 32 + q * 8];
            float4 sc1 = *(const float4*)&scs[k * 32 + q * 8 + 4];
            float4 sh0 = *(const float4*)&shs[k * 32 + q * 8];
            float4 sh1 = *(const float4*)&shs[k * 32 + q * 8 + 4];
            float scv[8] = {sc0.x, sc0.y, sc0.z, sc0.w, sc1.x, sc1.y, sc1.z, sc1.w};
            float shv[8] = {sh0.x, sh0.y, sh0.z, sh0.w, sh1.x, sh1.y, sh1.z, sh1.w};
            s16x8 bfrag;
            #pragma unroll
            for (int j = 0; j < 8; j++) {
                float f = fmaxf(fmaf(bf2f((unsigned short)raw[j]), scv[j], shv[j]), 0.0f);
                bfrag[j] = (short)f2bf(f);
            }
            #pragma unroll
            for (int mt = 0; mt < 9; mt++) {
                s16x8 af = *(const s16x8*)&wbfs_sw[(((k * 9 + mt) * 64) + lane) * 8];
                acc[mt] = __builtin_amdgcn_mfma_f32_16x16x32_bf16(af, bfrag, acc[mt], 0, 0, 0);
            }
        }
        #pragma unroll
        for (int mt = 0; mt < 9; mt++) {
            s16x4 hv;
            #pragma unroll
            for (int reg = 0; reg < 4; reg++)
                hv[reg] = (short)f2bf(acc[mt][reg] + bsp[mt * 16 + q * 4 + reg]);
            *(s16x4*)&kt[pl * 152 + mt * 16 + q * 4] = hv;
        }
    }
    __syncthreads();

    // ---- involution: kern from LDS, x from global ----
    {
        const int g = tid >> 4, grp = tid & 15;
        const int pix = p0 + grp * 4;             // 4-aligned, never crosses a row
        const int h = pix / W_, w0 = pix - h * W_;

        float kv[9][4];
        #pragma unroll
        for (int kk = 0; kk < 9; kk++)
            #pragma unroll
            for (int j = 0; j < 4; j++)
                kv[kk][j] = bf2f((unsigned short)kt[(grp * 4 + j) * 152 + kk * 16 + g]);

        const bool wl = (w0 > 0), wr = (w0 < W_ - 4);
        const float* xb2 = x + (size_t)(b * C_ + g * 16) * HW_;
        float* ob = out + (size_t)(b * C_ + g * 16) * HW_ + pix;

        #pragma unroll 4
        for (int d = 0; d < 16; d++) {
            const float* xd = xb2 + (size_t)d * HW_;
            float a0 = 0.f, a1 = 0.f, a2 = 0.f, a3 = 0.f;
            #pragma unroll
            for (int di = 0; di < 3; di++) {
                int hh = h + di - 1;
                if (hh < 0 || hh >= W_) continue;
                const float* rowp = xd + hh * W_ + w0;
                float4 m = *(const float4*)rowp;          // 16B-aligned
                float e0 = wl ? rowp[-1] : 0.f;
                float e5 = wr ? rowp[4]  : 0.f;
                float e[6] = {e0, m.x, m.y, m.z, m.w, e5};
                #pragma unroll
                for (int dj = 0; dj < 3; dj++) {
                    const float* kvt = kv[di * 3 + dj];
                    a0 = fmaf(e[0 + dj], kvt[0], a0);
                    a1 = fmaf(e[1 + dj], kvt[1], a1);
                    a2 = fmaf(e[2 + dj], kvt[2], a2);
                    a3 = fmaf(e[3 + dj], kvt[3], a3);
                }
            }
            *(float4*)(ob + (size_t)d * HW_) = make_float4(a0, a1, a2, a3);
        }
    }
}

extern "C" void kernel_launch(void* const* d_in, const int* in_sizes, int n_in,
                              void* d_out, int out_size, void* d_ws, size_t ws_size,
                              hipStream_t stream) {
    const float* x        = (const float*)d_in[0];
    const float* w_reduce = (const float*)d_in[1];
    // d_in[2] = b_reduce: unused — per-channel bias cancels exactly in BN.
    const float* gamma    = (const float*)d_in[3];
    const float* beta     = (const float*)d_in[4];
    const float* w_span   = (const float*)d_in[5];
    const float* b_span   = (const float*)d_in[6];
    float* out = (float*)d_out;

    char* wsb = (char*)d_ws;
    unsigned short* t_g     = (unsigned short*)(wsb + TG_OFF_B);
    float*          gp      = (float*)(wsb + GP_OFF_B);
    float*          stats   = (float*)(wsb + STAT_OFF_B);
    unsigned short* wbfr_sw = (unsigned short*)(wsb + WBFR_OFF_B);
    unsigned short* wbfs_sw = (unsigned short*)(wsb + WBFS_OFF_B);

    prep_cast<<<200, 256, 0, stream>>>(w_reduce, w_span, wbfr_sw, wbfs_sw);
    reduce_mfma<<<NBLK, 256, 0, stream>>>(x, wbfr_sw, t_g, gp);
    bn_finalize<<<128, 256, 0, stream>>>(gp, gamma, beta, stats);
    span_invol<<<NBLK, 256, 0, stream>>>(x, t_g, wbfs_sw, b_span, stats, out);
}